// Round 15
// baseline (86.297 us; speedup 1.0000x reference)
//
#include <hip/hip_runtime.h>
#include <stdint.h>
#include <math.h>

#define B_SZ   2048
#define D_SZ   128
#define C_SZ   100000
#define S_SC   30.0f
#define C2LOG  43.2808512f                // 30*log2(e)
#define M2LOG  12.9837726f                // 9*log2(e)
#define A_QS   173.1234048f               // fp8 quant scale for f: C2LOG*4
#define B_QS   256.0f                     // fp8 quant scale for w
#define SCL_A  0x7D7D7D7Du                // e8m0 125 = 2^-2 (all 4 bytes)
#define SCL_B  0x77777777u                // e8m0 119 = 2^-8

// ZERO-LDS streaming: 1-wave blocks (64 thr). afrag pinned in regs via
// volatile loads; B fragments streamed global->reg, perfectly coalesced
// (64 lanes = 16 cols x 128B contiguous). No LDS, no barriers, no ds_read.
#define BN     32                         // cols per subtile
#define NSUB   32
#define CPB    (BN*NSUB)                  // 1024 cols per block
#define GRID_C ((C_SZ + CPB - 1)/CPB)     // 98
#define C_PAD  (GRID_C*CPB)               // 100352
#define POST_SUB 352.0f                   // pad cols contribute 2^0 = 1 each
#define NSLOT  GRID_C                     // 98 partial slots per row

typedef float f32x4 __attribute__((ext_vector_type(4)));
typedef int   i32x4 __attribute__((ext_vector_type(4)));
typedef int   i32x8 __attribute__((ext_vector_type(8)));
typedef unsigned char u8;

// ------- row L2-normalize (x qscale) -> fp8 e4m3; rows >= valid_rows zeroed -------
__global__ void rownorm_fp8_kernel(const float* __restrict__ in,
                                   u8* __restrict__ out, int rows,
                                   int valid_rows, float scale) {
  int row  = (blockIdx.x * blockDim.x + threadIdx.x) >> 6;
  int lane = threadIdx.x & 63;
  if (row >= rows) return;
  if (row >= valid_rows) {
    ((unsigned short*)(out + (size_t)row * D_SZ))[lane] = 0;
    return;
  }
  float2 v = ((const float2*)(in + (size_t)row * D_SZ))[lane];
  float ss = v.x * v.x + v.y * v.y;
  #pragma unroll
  for (int m = 1; m < 64; m <<= 1) ss += __shfl_xor(ss, m, 64);
  float rn = scale / sqrtf(ss);
  int pk = __builtin_amdgcn_cvt_pk_fp8_f32(v.x * rn, v.y * rn, 0, false);
  ((unsigned short*)(out + (size_t)row * D_SZ))[lane] = (unsigned short)(pk & 0xFFFF);
}

// ------- fused: normalize+quantize f rows AND exact fp32 label cos -------
__global__ void prep_f_kernel(const float* __restrict__ f,
                              const int* __restrict__ labels,
                              const float* __restrict__ w,
                              u8* __restrict__ fn, float* __restrict__ cosy) {
  int row  = (blockIdx.x * blockDim.x + threadIdx.x) >> 6;
  int lane = threadIdx.x & 63;
  if (row >= B_SZ) return;
  float2 fv = ((const float2*)(f + (size_t)row * D_SZ))[lane];
  float ff = fv.x * fv.x + fv.y * fv.y;
  #pragma unroll
  for (int m = 1; m < 64; m <<= 1) ff += __shfl_xor(ff, m, 64);
  float rn = A_QS / sqrtf(ff);
  int pk = __builtin_amdgcn_cvt_pk_fp8_f32(fv.x * rn, fv.y * rn, 0, false);
  ((unsigned short*)(fn + (size_t)row * D_SZ))[lane] = (unsigned short)(pk & 0xFFFF);

  int y = labels[row];
  float2 wv = ((const float2*)(w + (size_t)y * D_SZ))[lane];
  float d  = fv.x * wv.x + fv.y * wv.y;
  float ww = wv.x * wv.x + wv.y * wv.y;
  #pragma unroll
  for (int m = 1; m < 64; m <<= 1) {
    d  += __shfl_xor(d,  m, 64);
    ww += __shfl_xor(ww, m, 64);
  }
  if (lane == 0) {
    float c = d / (sqrtf(ff) * sqrtf(ww));
    c = fminf(1.0f, fmaxf(-1.0f, c));
    cosy[row] = c;
  }
}

// ---------------- fused MX-FP8 MFMA GEMM + softmax partials ----------------
// 1 wave per block, ZERO LDS. Lane (l15,hi): hi=lane>>4 (0..3) covers K bytes
// hi*32..+32; l15 covers 16 rows/cols. afrag[i] = A rows r0+i*16+l15 (volatile
// loads: pinned, never rematerialized - the R2 lesson). B: per 16-col group,
// 2 x dwordx4 per lane, fully coalesced. 2-subtile unroll keeps 8 loads in
// flight; compiler inserts counted vmcnt waits. acc = 43.28*cos; s += 2^acc.
__global__ __launch_bounds__(64, 4) void gemm_partial_kernel(
    const u8* __restrict__ fn, const u8* __restrict__ wn,
    float* __restrict__ ps) {
  const int lane = threadIdx.x & 63;
  const int cb   = blockIdx.y;     // 0..97
  const int r0   = blockIdx.x * 64;
  const int hi   = lane >> 4;      // 0..3
  const int l15  = lane & 15;

  // ---- afrag: volatile global->reg (exactly-once, stays in registers) ----
  const u8* ap = fn + (size_t)(r0 + l15) * D_SZ + hi * 32;
  i32x8 afrag[4];
  #pragma unroll
  for (int i = 0; i < 4; ++i) {
    i32x4 lo = *(volatile const i32x4*)(ap + (size_t)i * 16 * D_SZ);
    i32x4 h4 = *(volatile const i32x4*)(ap + (size_t)i * 16 * D_SZ + 16);
    afrag[i] = __builtin_shufflevector(lo, h4, 0, 1, 2, 3, 4, 5, 6, 7);
  }

  // ---- B base: col cb*CPB + l15, K bytes hi*32 ----
  const u8* bp = wn + ((size_t)cb * CPB + l15) * D_SZ + hi * 32;
  // subtile s, phase j: addr = bp + (s*BN + j*16)*D_SZ, +16 for second half

  float sacc[4][4] = {};
  const f32x4 zero4 = {0.f, 0.f, 0.f, 0.f};

#define BLOAD(S, J, DEST)                                                     \
  {                                                                           \
    const u8* p = bp + (size_t)((S) * BN + (J) * 16) * D_SZ;                  \
    i32x4 lo = *(const i32x4*)p;                                              \
    i32x4 h4 = *(const i32x4*)(p + 16);                                       \
    DEST = __builtin_shufflevector(lo, h4, 0, 1, 2, 3, 4, 5, 6, 7);           \
  }
#define CLUSTER(BF)                                                           \
  {                                                                           \
    f32x4 acc[4];                                                             \
    __builtin_amdgcn_s_setprio(1);                                            \
    _Pragma("unroll")                                                         \
    for (int i = 0; i < 4; ++i)                                               \
      acc[i] = __builtin_amdgcn_mfma_scale_f32_16x16x128_f8f6f4(              \
          afrag[i], BF, zero4, 0, 0, 0, SCL_A, 0, SCL_B);                     \
    __builtin_amdgcn_s_setprio(0);                                            \
    _Pragma("unroll")                                                         \
    for (int i = 0; i < 4; ++i) {                                             \
      f32x4 a4 = acc[i];                                                      \
      _Pragma("unroll")                                                       \
      for (int r = 0; r < 4; ++r)                                             \
        sacc[i][r] += __builtin_amdgcn_exp2f(a4[r]);                          \
    }                                                                         \
  }

  #pragma unroll 1
  for (int t = 0; t < NSUB / 2; ++t) {
    int s0 = 2 * t;
    // issue all 8 loads for two subtiles up front (stay in flight)
    i32x8 b00, b01, b10, b11;
    BLOAD(s0,     0, b00);
    BLOAD(s0,     1, b01);
    BLOAD(s0 + 1, 0, b10);
    BLOAD(s0 + 1, 1, b11);
    CLUSTER(b00);
    CLUSTER(b01);
    CLUSTER(b10);
    CLUSTER(b11);
  }

  // ---- reduce across the 16 lanes sharing each row, write partials ----
  #pragma unroll
  for (int i = 0; i < 4; ++i)
    #pragma unroll
    for (int r = 0; r < 4; ++r) {
      float s = sacc[i][r];
      #pragma unroll
      for (int m = 1; m < 16; m <<= 1) s += __shfl_xor(s, m, 64);
      if (l15 == 0) {
        int rowg = r0 + i * 16 + hi * 4 + r;
        ps[(size_t)rowg * NSLOT + cb] = s;
      }
    }
#undef BLOAD
#undef CLUSTER
}

// ---------------- merge partials -> per-row loss ----------------
__global__ void merge_kernel(const float* __restrict__ ps,
                             const float* __restrict__ cosy,
                             float* __restrict__ losses) {
  int row  = (blockIdx.x * blockDim.x + threadIdx.x) >> 6;
  int lane = threadIdx.x & 63;
  if (row >= B_SZ) return;
  float s = 0.0f;
  for (int k = lane; k < NSLOT; k += 64) s += ps[(size_t)row * NSLOT + k];
  #pragma unroll
  for (int m = 1; m < 64; m <<= 1) s += __shfl_xor(s, m, 64);
  if (lane == 0) {
    float cy  = cosy[row];
    float zy2 = C2LOG * cy;                 // log2-domain label logit
    s = s - POST_SUB - exp2f(zy2) + exp2f(zy2 - M2LOG);
    s = fmaxf(s, 1e-30f);
    float lse = logf(s);
    losses[row] = lse - 0.9f * (S_SC * cy - 9.0f);
  }
}

// ---------------- deterministic mean over B ----------------
__global__ void final_kernel(const float* __restrict__ losses, float* __restrict__ out) {
  __shared__ float red[256];
  int tid = threadIdx.x;
  float s = 0.0f;
  for (int k = tid; k < B_SZ; k += 256) s += losses[k];
  red[tid] = s;
  __syncthreads();
  for (int off = 128; off > 0; off >>= 1) {
    if (tid < off) red[tid] += red[tid + off];
    __syncthreads();
  }
  if (tid == 0) out[0] = red[0] / (float)B_SZ;
}

extern "C" void kernel_launch(void* const* d_in, const int* in_sizes, int n_in,
                              void* d_out, int out_size, void* d_ws, size_t ws_size,
                              hipStream_t stream) {
  const float* feat   = (const float*)d_in[0];
  const int*   labels = (const int*)d_in[1];
  const float* weight = (const float*)d_in[2];
  float* out = (float*)d_out;

  char* ws = (char*)d_ws;
  size_t off = 0;
  u8* wn = (u8*)(ws + off);          off += (size_t)C_PAD * D_SZ;      // 12.85 MB
  off = (off + 255) & ~(size_t)255;
  u8* fn = (u8*)(ws + off);          off += (size_t)B_SZ * D_SZ;       // 256 KB
  off = (off + 255) & ~(size_t)255;
  float* cosy = (float*)(ws + off);  off += (size_t)B_SZ * 4;
  off = (off + 255) & ~(size_t)255;
  float* ps = (float*)(ws + off);    off += (size_t)B_SZ * NSLOT * 4;  // 0.8 MB
  off = (off + 255) & ~(size_t)255;
  float* losses = (float*)(ws + off);

  rownorm_fp8_kernel<<<(C_PAD + 3) / 4, 256, 0, stream>>>(weight, wn, C_PAD, C_SZ, B_QS);
  prep_f_kernel<<<(B_SZ + 3) / 4, 256, 0, stream>>>(feat, labels, weight, fn, cosy);

  dim3 grid(B_SZ / 64, GRID_C);   // 32 x 98 = 3136 one-wave blocks, no LDS
  gemm_partial_kernel<<<grid, 64, 0, stream>>>(fn, wn, ps);

  merge_kernel<<<(B_SZ + 3) / 4, 256, 0, stream>>>(ps, cosy, losses);
  final_kernel<<<1, 256, 0, stream>>>(losses, out);
}